// Round 8
// baseline (542.436 us; speedup 1.0000x reference)
//
#include <hip/hip_runtime.h>
#include <cstdint>
#include <cstddef>

// Problem constants (B,S,D,H fixed by the reference)
#define BB 2
#define SS 2048
#define DD 1024
#define HH 16
#define DHH 64
#define MROWS (BB*SS)   // 4096

typedef short short8 __attribute__((ext_vector_type(8)));
typedef short short4v __attribute__((ext_vector_type(4)));
typedef float floatx4 __attribute__((ext_vector_type(4)));
typedef float floatx16 __attribute__((ext_vector_type(16)));
typedef unsigned int uint4v __attribute__((ext_vector_type(4)));

#define GAS __attribute__((address_space(1)))
#define LAS __attribute__((address_space(3)))

__device__ __forceinline__ float4 ld4(const float* p) { return *(const float4*)p; }

// RNE float -> bf16 bits (no NaN inputs here)
__device__ __forceinline__ short f2bf(float x) {
    unsigned u = __builtin_bit_cast(unsigned, x);
    unsigned r = (u + 0x7fffu + ((u >> 16) & 1u)) >> 16;
    return (short)r;
}

// packed 2x f32 -> bf16 (RNE), single VALU op
__device__ __forceinline__ unsigned cvtpk(float lo, float hi) {
    unsigned r;
    asm("v_cvt_pk_bf16_f32 %0, %1, %2" : "=v"(r) : "v"(lo), "v"(hi));
    return r;
}

// async global->LDS, 16B per lane; LDS dest must be lane-contiguous per wave
__device__ __forceinline__ void gl_lds16(const short* g, short* l) {
    __builtin_amdgcn_global_load_lds((const GAS unsigned int*)g,
                                     (LAS unsigned int*)l, 16, 0, 0);
}

// ---------------------------------------------------------------------------
// fp32 -> bf16 row-major convert (query/key/value), 8 elems/thread
// grid = (MROWS*DD/2048, 1, 3)
// ---------------------------------------------------------------------------
__global__ __launch_bounds__(256) void convert_kernel(
    const float* __restrict__ s0, const float* __restrict__ s1, const float* __restrict__ s2,
    short* __restrict__ d0, short* __restrict__ d1, short* __restrict__ d2)
{
    const float* s; short* d;
    if (blockIdx.z == 0)      { s = s0; d = d0; }
    else if (blockIdx.z == 1) { s = s1; d = d1; }
    else                      { s = s2; d = d2; }
    size_t idx = ((size_t)blockIdx.x * 256 + threadIdx.x) * 8;
    float4 a = ld4(s + idx);
    float4 b = ld4(s + idx + 4);
    short8 p;
    p[0] = f2bf(a.x); p[1] = f2bf(a.y); p[2] = f2bf(a.z); p[3] = f2bf(a.w);
    p[4] = f2bf(b.x); p[5] = f2bf(b.y); p[6] = f2bf(b.z); p[7] = f2bf(b.w);
    *(short8*)(d + idx) = p;
}

// ---------------------------------------------------------------------------
// Weight transpose-convert: T[n][k] = bf16(W[k][n]), 1024x1024, 64x64 tiles.
// grid = (16, 16, 4)
// ---------------------------------------------------------------------------
__global__ __launch_bounds__(256) void transpose_w_kernel(
    const float* __restrict__ W0, const float* __restrict__ W1,
    const float* __restrict__ W2, const float* __restrict__ W3,
    short* __restrict__ T0, short* __restrict__ T1,
    short* __restrict__ T2, short* __restrict__ T3)
{
    const float* W; short* T;
    if (blockIdx.z == 0)      { W = W0; T = T0; }
    else if (blockIdx.z == 1) { W = W1; T = T1; }
    else if (blockIdx.z == 2) { W = W2; T = T2; }
    else                      { W = W3; T = T3; }

    __shared__ short tile[64 * 72];   // [n][k], stride 72 shorts
    const int t  = threadIdx.x;
    const int k0 = blockIdx.x * 64, n0 = blockIdx.y * 64;
#pragma unroll
    for (int i = 0; i < 4; i++) {
        int flat = i * 256 + t;              // float4 units
        int row = flat >> 4;                 // k within tile
        int c4  = (flat & 15) * 4;           // n within tile
        float4 v = ld4(W + (size_t)(k0 + row) * DD + n0 + c4);
        tile[(c4 + 0) * 72 + row] = f2bf(v.x);
        tile[(c4 + 1) * 72 + row] = f2bf(v.y);
        tile[(c4 + 2) * 72 + row] = f2bf(v.z);
        tile[(c4 + 3) * 72 + row] = f2bf(v.w);
    }
    __syncthreads();
#pragma unroll
    for (int i = 0; i < 4; i++) {
        int flat = i * 256 + t;              // short4 units
        int nrow = flat >> 4;
        int kc   = (flat & 15) * 4;
        short4v pk = *(short4v*)&tile[nrow * 72 + kc];
        *(short4v*)(T + (size_t)(n0 + nrow) * DD + k0 + kc) = pk;
    }
}

// ---------------------------------------------------------------------------
// BF16 MFMA GEMM (m97 structure): C[M,N] = A[M,K] @ Bt[N,K]^T + bias
// M=4096, N=K=1024. Tile 128x128, 256 thr (4 waves), wave=64x64, BK=32.
// ksplit: if nonzero, block z computes partial over K in [z*512,(z+1)*512)
// (bias still added per partial — caller compensates). grid = (8, 32, nz)
// ---------------------------------------------------------------------------
__global__ __launch_bounds__(256) void gemm_bf16_kernel(
    const short* __restrict__ A0, const short* __restrict__ A1, const short* __restrict__ A2,
    const short* __restrict__ Bt0, const short* __restrict__ Bt1, const short* __restrict__ Bt2,
    const float* __restrict__ b0, const float* __restrict__ b1, const float* __restrict__ b2,
    float* __restrict__ Cf0, float* __restrict__ Cf1, float* __restrict__ Cf2,
    short* __restrict__ Cb0, short* __restrict__ Cb1, short* __restrict__ Cb2,
    short* __restrict__ Ct0, short* __restrict__ Ct1, short* __restrict__ Ct2,
    float cs0, float cs1, float cs2, int ksplit)
{
    const short* A; const short* Bt; const float* bias;
    float* Cf; short* Cb; short* Ct; float cbs;
    if (blockIdx.z == 0)      { A = A0; Bt = Bt0; bias = b0; Cf = Cf0; Cb = Cb0; Ct = Ct0; cbs = cs0; }
    else if (blockIdx.z == 1) { A = A1; Bt = Bt1; bias = b1; Cf = Cf1; Cb = Cb1; Ct = Ct1; cbs = cs1; }
    else                      { A = A2; Bt = Bt2; bias = b2; Cf = Cf2; Cb = Cb2; Ct = Ct2; cbs = cs2; }

    __shared__ __align__(16) short As[128 * 32];
    __shared__ __align__(16) short Bs[128 * 32];

    const int tid  = threadIdx.x;
    const int lane = tid & 63;
    const int wave = tid >> 6;
    const int quad = lane >> 4;
    const int l15  = lane & 15;
    const int m0 = blockIdx.y * 128;
    const int n0 = blockIdx.x * 128;
    const int wr = (wave >> 1) * 64;   // wave m-offset
    const int wc = (wave & 1) * 64;    // wave n-offset

    const int kbeg = ksplit ? (int)blockIdx.z * 512 : 0;
    const int kend = ksplit ? kbeg + 512 : DD;

    floatx4 acc[4][4];
#pragma unroll
    for (int mt = 0; mt < 4; mt++)
#pragma unroll
        for (int nt = 0; nt < 4; nt++) acc[mt][nt] = (floatx4)0.0f;

    for (int k0 = kbeg; k0 < kend; k0 += 32) {
        __syncthreads();
#pragma unroll
        for (int j = 0; j < 2; j++) {
            int chunk = j * 256 + tid;        // 16B chunk id, lane-contiguous
            int row = chunk >> 2;             // tile row
            int ch  = chunk & 3;              // 8-elem chunk within 32-k row
            gl_lds16(A  + (size_t)(m0 + row) * DD + k0 + ch * 8, &As[chunk * 8]);
            gl_lds16(Bt + (size_t)(n0 + row) * DD + k0 + ch * 8, &Bs[chunk * 8]);
        }
        __syncthreads();

        short8 af[4], bf[4];
#pragma unroll
        for (int mt = 0; mt < 4; mt++)
            af[mt] = *(const short8*)&As[(wr + mt * 16 + l15) * 32 + quad * 8];
#pragma unroll
        for (int nt = 0; nt < 4; nt++)
            bf[nt] = *(const short8*)&Bs[(wc + nt * 16 + l15) * 32 + quad * 8];
#pragma unroll
        for (int mt = 0; mt < 4; mt++)
#pragma unroll
            for (int nt = 0; nt < 4; nt++)
                acc[mt][nt] = __builtin_amdgcn_mfma_f32_16x16x32_bf16(af[mt], bf[nt], acc[mt][nt], 0, 0, 0);
    }

    float biasv[4];
#pragma unroll
    for (int nt = 0; nt < 4; nt++) biasv[nt] = bias[n0 + wc + nt * 16 + l15];

    if (Cf || Cb) {
#pragma unroll
        for (int mt = 0; mt < 4; mt++)
#pragma unroll
            for (int r = 0; r < 4; r++) {
                const int m = m0 + wr + mt * 16 + quad * 4 + r;
                const size_t rowb = (size_t)m * DD + n0 + wc;
#pragma unroll
                for (int nt = 0; nt < 4; nt++) {
                    float v = acc[mt][nt][r] + biasv[nt];
                    if (Cf) Cf[rowb + nt * 16 + l15] = v;
                    if (Cb) Cb[rowb + nt * 16 + l15] = f2bf(v * cbs);
                }
            }
    }
    if (Ct) {
#pragma unroll
        for (int mt = 0; mt < 4; mt++) {
            const int mbase = m0 + wr + mt * 16 + quad * 4;
            const int bb = mbase >> 11;       // batch (tiles don't cross batch)
            const int s0 = mbase & 2047;
#pragma unroll
            for (int nt = 0; nt < 4; nt++) {
                const int c = n0 + wc + nt * 16 + l15;   // = h*64 + d
                short4v pk;
#pragma unroll
                for (int r = 0; r < 4; r++) pk[r] = f2bf(acc[mt][nt][r] + biasv[nt]);
                *(short4v*)(Ct + ((size_t)(bb * 1024 + c)) * SS + s0) = pk;
            }
        }
    }
}

// ---------------------------------------------------------------------------
// Repack K and V^T into MFMA-fragment order + precompute mask addend.
//  Kf block (b,h,kg32): [ks(4)][lane(64)][8] shorts, 2048 shorts/block.
//  Vf block (b,h,kt64): [tp(4)][dg(2)][lane(64)][8] shorts, 4096 shorts/block.
//  maddf[b*2048 + s] = (1 - mask[b][s]) * -1e9
// grid = (128, 1, 2): z=0 K; z=1 x<64 V, x=64/65 madd.
// ---------------------------------------------------------------------------
__global__ __launch_bounds__(256) void repack_kernel(
    const short* __restrict__ Kb, const short* __restrict__ Vt,
    const int* __restrict__ mask,
    short* __restrict__ Kf, short* __restrict__ Vf, float* __restrict__ maddf)
{
    const int t = threadIdx.x;
    if (blockIdx.z == 0) {
        const int b = blockIdx.x >> 6, kg = blockIdx.x & 63;
#pragma unroll
        for (int i = 0; i < 16; i++) {
            const int h = i, ks = t >> 6, lane = t & 63;
            const int c = lane & 31, hi = lane >> 5;
            short8 v = *(const short8*)(Kb + (size_t)(b * 2048 + kg * 32 + c) * 1024
                                        + h * 64 + ks * 16 + hi * 8);
            *(short8*)(Kf + ((size_t)((b * 16 + h) * 64 + kg)) * 2048 + ks * 512 + lane * 8) = v;
        }
    } else if (blockIdx.x < 64) {
        const int b = blockIdx.x >> 5, kt = blockIdx.x & 31;
#pragma unroll
        for (int i = 0; i < 32; i++) {
            const int flat = i * 256 + t;
            const int h = flat >> 9, rest = flat & 511;
            const int tp = rest >> 7, dg = (rest >> 6) & 1, lane = rest & 63;
            const int c = lane & 31, hi = lane >> 5;
            short8 v = *(const short8*)(Vt + (size_t)(b * 1024 + h * 64 + dg * 32 + c) * 2048
                                        + kt * 64 + tp * 16 + hi * 8);
            *(short8*)(Vf + ((size_t)((b * 16 + h) * 32 + kt)) * 4096
                       + (tp * 2 + dg) * 512 + lane * 8) = v;
        }
    } else if (blockIdx.x < 66) {
        const int b = blockIdx.x - 64;
#pragma unroll
        for (int j = 0; j < 8; j++) {
            const int idx = t * 8 + j;
            maddf[b * 2048 + idx] = (1.0f - (float)mask[b * 2048 + idx]) * -1e9f;
        }
    }
}

// ---------------------------------------------------------------------------
// BF16 MFMA attention — KEY-SPLIT, 512 thr / 8 waves: 4 q-subtiles x 2
// key-halves. Each wave free-runs 16 of the 32 key-tiles (no barriers in
// the loop); partial O/lsum merged via one LDS exchange at the end
// (exact for absolute-exp softmax: disjoint key sets sum directly).
// 16 waves/CU (4/SIMD) — double r6's concurrency on the latency chain.
//  - 32x32x16 fragments, exp2-domain softmax, swapped QK^T, in-register P
//    via cvtpk + v_permlane32_swap_b32 (r5/r6-verified math, bit-identical).
//  - operands from repacked Kf/Vf (coalesced 1KB loads, L1/L2-shared).
//  - kf double-buffered one tile ahead; vf at loop top; T5 setprio.
// Fuses +q residual and per-head LayerNorm. Writes fp32 X and bf16 Xb.
// ---------------------------------------------------------------------------
__device__ __forceinline__ void attn_tile(
    const short8 (&kf)[2][4], const short8 (&vf)[8], const short8 (&qf)[4],
    const float* mdb, int kt, floatx16 (&o)[2], float& lsum)
{
#pragma unroll
    for (int g = 0; g < 2; g++) {
        floatx16 acc = (floatx16)0.0f;
        __builtin_amdgcn_s_setprio(1);
#pragma unroll
        for (int ks = 0; ks < 4; ks++)
            acc = __builtin_amdgcn_mfma_f32_32x32x16_bf16(kf[g][ks], qf[ks], acc, 0, 0, 0);
        __builtin_amdgcn_s_setprio(0);
        float p[16];
#pragma unroll
        for (int a = 0; a < 4; a++) {
            float4 mr = *(const float4*)(mdb + kt * 64 + g * 32 + a * 8);
            p[4 * a + 0] = __builtin_exp2f(acc[4 * a + 0] + mr.x);
            p[4 * a + 1] = __builtin_exp2f(acc[4 * a + 1] + mr.y);
            p[4 * a + 2] = __builtin_exp2f(acc[4 * a + 2] + mr.z);
            p[4 * a + 3] = __builtin_exp2f(acc[4 * a + 3] + mr.w);
        }
        lsum += ((p[0] + p[1]) + (p[2] + p[3])) + ((p[4] + p[5]) + (p[6] + p[7]))
              + ((p[8] + p[9]) + (p[10] + p[11])) + ((p[12] + p[13]) + (p[14] + p[15]));
#pragma unroll
        for (int t2 = 0; t2 < 2; t2++) {
            unsigned w0 = cvtpk(p[8 * t2 + 0], p[8 * t2 + 1]);
            unsigned w1 = cvtpk(p[8 * t2 + 2], p[8 * t2 + 3]);
            unsigned w2 = cvtpk(p[8 * t2 + 4], p[8 * t2 + 5]);
            unsigned w3 = cvtpk(p[8 * t2 + 6], p[8 * t2 + 7]);
            asm volatile("v_permlane32_swap_b32 %0, %1" : "+v"(w0), "+v"(w2));
            asm volatile("v_permlane32_swap_b32 %0, %1" : "+v"(w1), "+v"(w3));
            uint4v u = {w0, w1, w2, w3};
            short8 pa = __builtin_bit_cast(short8, u);
            __builtin_amdgcn_s_setprio(1);
#pragma unroll
            for (int dg = 0; dg < 2; dg++)
                o[dg] = __builtin_amdgcn_mfma_f32_32x32x16_bf16(
                    pa, vf[(g * 2 + t2) * 2 + dg], o[dg], 0, 0, 0);
            __builtin_amdgcn_s_setprio(0);
        }
    }
}

__global__ __launch_bounds__(512, 4) void attn_mfma_kernel(
    const short* __restrict__ Qb, const short* __restrict__ Kf, const short* __restrict__ Vf,
    const float* __restrict__ Qf, const float* __restrict__ maddf,
    const float* __restrict__ g_att, const float* __restrict__ b_att,
    float* __restrict__ X, short* __restrict__ Xb)
{
    const int tid  = threadIdx.x;
    const int lane = tid & 63;
    const int wave = tid >> 6;          // 0..7
    const int qsub = wave >> 1;         // 0..3 q-subtile
    const int kh   = wave & 1;          // key half
    const int hi   = lane >> 5;
    const int c    = lane & 31;

    const int h  = blockIdx.y;
    const int b  = blockIdx.z;
    const int q0 = blockIdx.x * 128;
    const int bS = b * SS;

    __shared__ float olds[4][32][64];   // [qsub][reg][lane] partial O, 32 KB
    __shared__ float lsums[4][64];      // partial lsum

    const short* kfb = Kf + ((size_t)(b * 16 + h) * 64) * 2048 + lane * 8;
    const short* vfb = Vf + ((size_t)(b * 16 + h) * 32) * 4096 + lane * 8;
    const float* mdb = maddf + b * 2048 + hi * 4;

    // Q B-fragments: n = q = c, k = d = ks*16 + hi*8 + e  (pre-scaled bf16)
    short8 qf[4];
#pragma unroll
    for (int ks = 0; ks < 4; ks++)
        qf[ks] = *(const short8*)(Qb +
            (size_t)(bS + q0 + qsub * 32 + c) * DD + h * 64 + ks * 16 + hi * 8);

    floatx16 o[2];
    o[0] = (floatx16)0.0f;
    o[1] = (floatx16)0.0f;
    float lsum = 0.0f;

    const int kbase = kh * 16;          // this wave's 16 tiles
    short8 kfA[2][4], kfB[2][4], vf[8];
#pragma unroll
    for (int g = 0; g < 2; g++)
#pragma unroll
        for (int ks = 0; ks < 4; ks++)
            kfA[g][ks] = *(const short8*)(kfb + (size_t)(kbase * 2 + g) * 2048 + ks * 512);

    for (int kt = kbase; kt < kbase + 16; kt += 2) {
#pragma unroll
        for (int j = 0; j < 8; j++)
            vf[j] = *(const short8*)(vfb + (size_t)kt * 4096 + j * 512);
#pragma unroll
        for (int g = 0; g < 2; g++)
#pragma unroll
            for (int ks = 0; ks < 4; ks++)
                kfB[g][ks] = *(const short8*)(kfb + (size_t)((kt + 1) * 2 + g) * 2048 + ks * 512);
        attn_tile(kfA, vf, qf, mdb, kt, o, lsum);

#pragma unroll
        for (int j = 0; j < 8; j++)
            vf[j] = *(const short8*)(vfb + (size_t)(kt + 1) * 4096 + j * 512);
        const int ktn = (kt + 2 < kbase + 16) ? (kt + 2) : (kbase + 15);
#pragma unroll
        for (int g = 0; g < 2; g++)
#pragma unroll
            for (int ks = 0; ks < 4; ks++)
                kfA[g][ks] = *(const short8*)(kfb + (size_t)(ktn * 2 + g) * 2048 + ks * 512);
        attn_tile(kfB, vf, qf, mdb, kt + 1, o, lsum);
    }

    // merge key-half partials (exact: disjoint key sets)
    if (kh == 1) {
#pragma unroll
        for (int r = 0; r < 16; r++) {
            olds[qsub][r][lane]      = o[0][r];
            olds[qsub][16 + r][lane] = o[1][r];
        }
        lsums[qsub][lane] = lsum;
    }
    __syncthreads();
    if (kh == 1) return;
#pragma unroll
    for (int r = 0; r < 16; r++) {
        o[0][r] += olds[qsub][r][lane];
        o[1][r] += olds[qsub][16 + r][lane];
    }
    lsum += lsums[qsub][lane];

    // total softmax denom for q = c (partner lane holds the other 32 keys)
    lsum += __shfl_xor(lsum, 32);
    const float rl = 1.0f / lsum;

    const float g0v = g_att[c], g1v = g_att[32 + c];
    const float b0v = b_att[c], b1v = b_att[32 + c];

#pragma unroll
    for (int r = 0; r < 16; r++) {
        const int rloc = (r & 3) + 8 * (r >> 2) + 4 * hi;   // q within subtile
        const float rlr = __shfl(rl, rloc);
        const int row = q0 + qsub * 32 + rloc;
        const size_t base = (size_t)(bS + row) * DD + h * 64;
        float x0 = o[0][r] * rlr + Qf[base + c];
        float x1 = o[1][r] * rlr + Qf[base + 32 + c];
        float s = x0 + x1;
#pragma unroll
        for (int off = 1; off < 32; off <<= 1) s += __shfl_xor(s, off);
        const float mu = s * (1.0f / 64.0f);
        float d0 = x0 - mu, d1 = x1 - mu;
        float v = d0 * d0 + d1 * d1;
#pragma unroll
        for (int off = 1; off < 32; off <<= 1) v += __shfl_xor(v, off);
        const float rstd = rsqrtf(v * (1.0f / 64.0f) + 1e-5f);
        float y0 = d0 * rstd * g0v + b0v;
        float y1 = d1 * rstd * g1v + b1v;
        X[base + c]      = y0;
        X[base + 32 + c] = y1;
        Xb[base + c]      = f2bf(y0);
        Xb[base + 32 + c] = f2bf(y1);
    }
}

// ---------------------------------------------------------------------------
// Final fused epilogue: Z = X + tanh(Y1 + Y2 - bres);  out = tanh(LN(Z, g, b))
// (Y1/Y2 are K-split GEMM partials, each carrying +bres — subtract one.)
// ---------------------------------------------------------------------------
__global__ __launch_bounds__(256) void lnout_kernel(
    const float* __restrict__ X, const float* __restrict__ Y1,
    const float* __restrict__ Y2, const float* __restrict__ bres,
    const float* __restrict__ g, const float* __restrict__ bcoef,
    float* __restrict__ out)
{
    const int r = blockIdx.x;
    const int t = threadIdx.x;
    const size_t base = (size_t)r * DD + (t << 2);
    float4 x  = ld4(X + base);
    float4 y1 = ld4(Y1 + base);
    float4 y2 = ld4(Y2 + base);
    float4 br = ld4(bres + (t << 2));
    float4 z;
    z.x = x.x + tanhf(y1.x + y2.x - br.x);
    z.y = x.y + tanhf(y1.y + y2.y - br.y);
    z.z = x.z + tanhf(y1.z + y2.z - br.z);
    z.w = x.w + tanhf(y1.w + y2.w - br.w);

    __shared__ float red[4];
    __shared__ float stats[2];
    const int w = t >> 6;

    float sv = z.x + z.y + z.z + z.w;
#pragma unroll
    for (int off = 32; off > 0; off >>= 1) sv += __shfl_down(sv, off);
    if ((t & 63) == 0) red[w] = sv;
    __syncthreads();
    if (t == 0) stats[0] = (red[0] + red[1] + red[2] + red[3]) * (1.0f / 1024.0f);
    __syncthreads();
    const float mu = stats[0];

    float4 d;
    d.x = z.x - mu; d.y = z.y - mu; d.z = z.z - mu; d.w = z.w - mu;
    float s2 = d.x * d.x + d.y * d.y + d.z * d.z + d.w * d.w;
#pragma unroll
    for (int off = 32; off > 0; off >>= 1) s2 += __shfl_down(s2, off);
    if ((t & 63) == 0) red[w] = s2;
    __syncthreads();
    if (t == 0) stats[1] = rsqrtf((red[0] + red[1] + red[2] + red[3]) * (1.0f / 1024.0f) + 1e-5f);
    __syncthreads();
    const float rstd = stats[1];

    float4 gv = ld4(g + (t << 2));
    float4 bv = ld4(bcoef + (t << 2));
    float4 o;
    o.x = tanhf(d.x * rstd * gv.x + bv.x);
    o.y = tanhf(d.y * rstd * gv.y + bv.y);
    o.z = tanhf(d.z * rstd * gv.z + bv.z);
    o.w = tanhf(d.w * rstd * gv.w + bv.w);
    *(float4*)(out + base) = o;
}

// ---------------------------------------------------------------------------
extern "C" void kernel_launch(void* const* d_in, const int* in_sizes, int n_in,
                              void* d_out, int out_size, void* d_ws, size_t ws_size,
                              hipStream_t stream)
{
    const float* query = (const float*)d_in[0];
    const float* key   = (const float*)d_in[1];
    const float* value = (const float*)d_in[2];
    const int*   mask  = (const int*)  d_in[3];
    const float* Wq    = (const float*)d_in[4];
    const float* bq    = (const float*)d_in[5];
    const float* Wk    = (const float*)d_in[6];
    const float* bk    = (const float*)d_in[7];
    const float* Wv    = (const float*)d_in[8];
    const float* bv    = (const float*)d_in[9];
    const float* g_att = (const float*)d_in[10];
    const float* b_att = (const float*)d_in[11];
    const float* Wres  = (const float*)d_in[12];
    const float* bres  = (const float*)d_in[13];
    const float* g_out = (const float*)d_in[14];
    const float* b_out = (const float*)d_in[15];

    const size_t MAT = (size_t)MROWS * DD;     // 4M elements
    float* fws = (float*)d_ws;
    // fp32 regions
    float* Qw = fws;                           // [0,4M)   fp32 Q residual
    float* Xw = fws + MAT;                     // [4M,8M)  attn out fp32
    // bf16 persistent regions (element = short)
    short* Qb = (short*)(fws + 2 * MAT);       // 2M floats (holds Q*0.125*log2e in bf16)
    short* Kb = Qb + MAT;
    short* Vt = Kb + MAT;                      // V^T [(b*1024+h*64+d)][S]
    // bf16 inputs to QKV GEMM (dead after) — reused later
    short* qbf = Vt + MAT;                     // 2M floats
    short* kbf = qbf + MAT;
    short* vbf = kbf + MAT;
    // weight transposes
    short* Wtq = vbf + MAT;                    // 0.5M floats each
    short* Wtk = Wtq + DD * DD;
    short* Wtv = Wtk + DD * DD;
    short* Wtr = Wtv + DD * DD;
    float* maddf = (float*)(Wtr + DD * DD);    // 4096 floats mask addend
    // aliases (stream-ordered safe):
    short* Xb = qbf;                           // attn bf16 out (qbf dead)
    short* Kf = vbf;                           // fragment-packed K (vbf dead post-GEMM)
    short* Vf = kbf;                           // fragment-packed V (kbf dead post-GEMM)
    float* Y1 = (float*)kbf;                   // res partial 1 (kbf+vbf dead post-attn)
    float* Y2 = Qw;                            // res partial 2 (Qw dead post-attn)

    // 1) fp32 -> bf16 activations
    convert_kernel<<<dim3(MAT / 2048, 1, 3), 256, 0, stream>>>(
        query, key, value, qbf, kbf, vbf);

    // 2) weight transpose-converts
    transpose_w_kernel<<<dim3(16, 16, 4), 256, 0, stream>>>(
        Wq, Wk, Wv, Wres, Wtq, Wtk, Wtv, Wtr);

    // 3) QKV projections, bf16 MFMA. Q: fp32 + bf16*(0.125*log2e); K; V^T
    gemm_bf16_kernel<<<dim3(8, 32, 3), 256, 0, stream>>>(
        qbf, kbf, vbf, Wtq, Wtk, Wtv, bq, bk, bv,
        Qw, nullptr, nullptr,
        Qb, Kb, nullptr,
        nullptr, nullptr, Vt,
        0.180336884f, 1.0f, 1.0f, 0);

    // 3.5) repack K/V into MFMA-fragment order + mask addend
    repack_kernel<<<dim3(128, 1, 2), 256, 0, stream>>>(
        Kb, Vt, mask, Kf, Vf, maddf);

    // 4) key-split barrier-light bf16 MFMA attention + residual + per-head LN
    attn_mfma_kernel<<<dim3(SS / 128, HH, BB), 512, 0, stream>>>(
        Qb, Kf, Vf, Qw, maddf, g_att, b_att, Xw, Xb);

    // 5) res branch GEMM, K-split x2: Y1/Y2 partials (each +bres)
    gemm_bf16_kernel<<<dim3(8, 32, 2), 256, 0, stream>>>(
        Xb, Xb, Xb, Wtr, Wtr, Wtr, bres, bres, bres,
        Y1, Y2, nullptr, nullptr, nullptr, nullptr, nullptr, nullptr, nullptr,
        1.0f, 1.0f, 1.0f, 1);

    // 6) Z = X + tanh(Y1+Y2-bres); out = tanh(LN(Z))
    lnout_kernel<<<MROWS, 256, 0, stream>>>(Xw, Y1, Y2, bres, g_out, b_out, (float*)d_out);
}

// Round 9
// 273.606 us; speedup vs baseline: 1.9825x; 1.9825x over previous
//
#include <hip/hip_runtime.h>
#include <cstdint>
#include <cstddef>

// Problem constants (B,S,D,H fixed by the reference)
#define BB 2
#define SS 2048
#define DD 1024
#define HH 16
#define DHH 64
#define MROWS (BB*SS)   // 4096

typedef short short8 __attribute__((ext_vector_type(8)));
typedef short short4v __attribute__((ext_vector_type(4)));
typedef float floatx4 __attribute__((ext_vector_type(4)));
typedef unsigned int uint2v __attribute__((ext_vector_type(2)));

#define GAS __attribute__((address_space(1)))
#define LAS __attribute__((address_space(3)))

__device__ __forceinline__ float4 ld4(const float* p) { return *(const float4*)p; }

// RNE float -> bf16 bits (no NaN inputs here)
__device__ __forceinline__ short f2bf(float x) {
    unsigned u = __builtin_bit_cast(unsigned, x);
    unsigned r = (u + 0x7fffu + ((u >> 16) & 1u)) >> 16;
    return (short)r;
}

// packed 2x f32 -> bf16 (RNE), single VALU op
__device__ __forceinline__ unsigned cvtpk(float lo, float hi) {
    unsigned r;
    asm("v_cvt_pk_bf16_f32 %0, %1, %2" : "=v"(r) : "v"(lo), "v"(hi));
    return r;
}

// async global->LDS, 16B per lane; LDS dest must be lane-contiguous per wave
__device__ __forceinline__ void gl_lds16(const short* g, short* l) {
    __builtin_amdgcn_global_load_lds((const GAS unsigned int*)g,
                                     (LAS unsigned int*)l, 16, 0, 0);
}

// ---------------------------------------------------------------------------
// fp32 -> bf16 row-major convert (query/key/value), 8 elems/thread
// grid = (MROWS*DD/2048, 1, 3)
// ---------------------------------------------------------------------------
__global__ __launch_bounds__(256) void convert_kernel(
    const float* __restrict__ s0, const float* __restrict__ s1, const float* __restrict__ s2,
    short* __restrict__ d0, short* __restrict__ d1, short* __restrict__ d2)
{
    const float* s; short* d;
    if (blockIdx.z == 0)      { s = s0; d = d0; }
    else if (blockIdx.z == 1) { s = s1; d = d1; }
    else                      { s = s2; d = d2; }
    size_t idx = ((size_t)blockIdx.x * 256 + threadIdx.x) * 8;
    float4 a = ld4(s + idx);
    float4 b = ld4(s + idx + 4);
    short8 p;
    p[0] = f2bf(a.x); p[1] = f2bf(a.y); p[2] = f2bf(a.z); p[3] = f2bf(a.w);
    p[4] = f2bf(b.x); p[5] = f2bf(b.y); p[6] = f2bf(b.z); p[7] = f2bf(b.w);
    *(short8*)(d + idx) = p;
}

// ---------------------------------------------------------------------------
// Weight transpose-convert: T[n][k] = bf16(W[k][n]), 1024x1024, 64x64 tiles.
// grid = (16, 16, 4)
// ---------------------------------------------------------------------------
__global__ __launch_bounds__(256) void transpose_w_kernel(
    const float* __restrict__ W0, const float* __restrict__ W1,
    const float* __restrict__ W2, const float* __restrict__ W3,
    short* __restrict__ T0, short* __restrict__ T1,
    short* __restrict__ T2, short* __restrict__ T3)
{
    const float* W; short* T;
    if (blockIdx.z == 0)      { W = W0; T = T0; }
    else if (blockIdx.z == 1) { W = W1; T = T1; }
    else if (blockIdx.z == 2) { W = W2; T = T2; }
    else                      { W = W3; T = T3; }

    __shared__ short tile[64 * 72];   // [n][k], stride 72 shorts
    const int t  = threadIdx.x;
    const int k0 = blockIdx.x * 64, n0 = blockIdx.y * 64;
#pragma unroll
    for (int i = 0; i < 4; i++) {
        int flat = i * 256 + t;              // float4 units
        int row = flat >> 4;                 // k within tile
        int c4  = (flat & 15) * 4;           // n within tile
        float4 v = ld4(W + (size_t)(k0 + row) * DD + n0 + c4);
        tile[(c4 + 0) * 72 + row] = f2bf(v.x);
        tile[(c4 + 1) * 72 + row] = f2bf(v.y);
        tile[(c4 + 2) * 72 + row] = f2bf(v.z);
        tile[(c4 + 3) * 72 + row] = f2bf(v.w);
    }
    __syncthreads();
#pragma unroll
    for (int i = 0; i < 4; i++) {
        int flat = i * 256 + t;              // short4 units
        int nrow = flat >> 4;
        int kc   = (flat & 15) * 4;
        short4v pk = *(short4v*)&tile[nrow * 72 + kc];
        *(short4v*)(T + (size_t)(n0 + nrow) * DD + k0 + kc) = pk;
    }
}

// ---------------------------------------------------------------------------
// BF16 MFMA GEMM (m97 structure): C[M,N] = A[M,K] @ Bt[N,K]^T + bias
// M=4096, N=K=1024. Tile 128x128, 256 thr (4 waves), wave=64x64, BK=32.
// ksplit: if nonzero, block z computes partial over K in [z*512,(z+1)*512)
// (bias still added per partial — caller compensates). grid = (8, 32, nz)
// ---------------------------------------------------------------------------
__global__ __launch_bounds__(256) void gemm_bf16_kernel(
    const short* __restrict__ A0, const short* __restrict__ A1, const short* __restrict__ A2,
    const short* __restrict__ Bt0, const short* __restrict__ Bt1, const short* __restrict__ Bt2,
    const float* __restrict__ b0, const float* __restrict__ b1, const float* __restrict__ b2,
    float* __restrict__ Cf0, float* __restrict__ Cf1, float* __restrict__ Cf2,
    short* __restrict__ Cb0, short* __restrict__ Cb1, short* __restrict__ Cb2,
    short* __restrict__ Ct0, short* __restrict__ Ct1, short* __restrict__ Ct2,
    float cs0, float cs1, float cs2, int ksplit)
{
    const short* A; const short* Bt; const float* bias;
    float* Cf; short* Cb; short* Ct; float cbs;
    if (blockIdx.z == 0)      { A = A0; Bt = Bt0; bias = b0; Cf = Cf0; Cb = Cb0; Ct = Ct0; cbs = cs0; }
    else if (blockIdx.z == 1) { A = A1; Bt = Bt1; bias = b1; Cf = Cf1; Cb = Cb1; Ct = Ct1; cbs = cs1; }
    else                      { A = A2; Bt = Bt2; bias = b2; Cf = Cf2; Cb = Cb2; Ct = Ct2; cbs = cs2; }

    __shared__ __align__(16) short As[128 * 32];
    __shared__ __align__(16) short Bs[128 * 32];

    const int tid  = threadIdx.x;
    const int lane = tid & 63;
    const int wave = tid >> 6;
    const int quad = lane >> 4;
    const int l15  = lane & 15;
    const int m0 = blockIdx.y * 128;
    const int n0 = blockIdx.x * 128;
    const int wr = (wave >> 1) * 64;   // wave m-offset
    const int wc = (wave & 1) * 64;    // wave n-offset

    const int kbeg = ksplit ? (int)blockIdx.z * 512 : 0;
    const int kend = ksplit ? kbeg + 512 : DD;

    floatx4 acc[4][4];
#pragma unroll
    for (int mt = 0; mt < 4; mt++)
#pragma unroll
        for (int nt = 0; nt < 4; nt++) acc[mt][nt] = (floatx4)0.0f;

    for (int k0 = kbeg; k0 < kend; k0 += 32) {
        __syncthreads();
#pragma unroll
        for (int j = 0; j < 2; j++) {
            int chunk = j * 256 + tid;        // 16B chunk id, lane-contiguous
            int row = chunk >> 2;             // tile row
            int ch  = chunk & 3;              // 8-elem chunk within 32-k row
            gl_lds16(A  + (size_t)(m0 + row) * DD + k0 + ch * 8, &As[chunk * 8]);
            gl_lds16(Bt + (size_t)(n0 + row) * DD + k0 + ch * 8, &Bs[chunk * 8]);
        }
        __syncthreads();

        short8 af[4], bf[4];
#pragma unroll
        for (int mt = 0; mt < 4; mt++)
            af[mt] = *(const short8*)&As[(wr + mt * 16 + l15) * 32 + quad * 8];
#pragma unroll
        for (int nt = 0; nt < 4; nt++)
            bf[nt] = *(const short8*)&Bs[(wc + nt * 16 + l15) * 32 + quad * 8];
#pragma unroll
        for (int mt = 0; mt < 4; mt++)
#pragma unroll
            for (int nt = 0; nt < 4; nt++)
                acc[mt][nt] = __builtin_amdgcn_mfma_f32_16x16x32_bf16(af[mt], bf[nt], acc[mt][nt], 0, 0, 0);
    }

    float biasv[4];
#pragma unroll
    for (int nt = 0; nt < 4; nt++) biasv[nt] = bias[n0 + wc + nt * 16 + l15];

    if (Cf || Cb) {
#pragma unroll
        for (int mt = 0; mt < 4; mt++)
#pragma unroll
            for (int r = 0; r < 4; r++) {
                const int m = m0 + wr + mt * 16 + quad * 4 + r;
                const size_t rowb = (size_t)m * DD + n0 + wc;
#pragma unroll
                for (int nt = 0; nt < 4; nt++) {
                    float v = acc[mt][nt][r] + biasv[nt];
                    if (Cf) Cf[rowb + nt * 16 + l15] = v;
                    if (Cb) Cb[rowb + nt * 16 + l15] = f2bf(v * cbs);
                }
            }
    }
    if (Ct) {
#pragma unroll
        for (int mt = 0; mt < 4; mt++) {
            const int mbase = m0 + wr + mt * 16 + quad * 4;
            const int bb = mbase >> 11;       // batch (tiles don't cross batch)
            const int s0 = mbase & 2047;
#pragma unroll
            for (int nt = 0; nt < 4; nt++) {
                const int c = n0 + wc + nt * 16 + l15;   // = h*64 + d
                short4v pk;
#pragma unroll
                for (int r = 0; r < 4; r++) pk[r] = f2bf(acc[mt][nt][r] + biasv[nt]);
                *(short4v*)(Ct + ((size_t)(bb * 1024 + c)) * SS + s0) = pk;
            }
        }
    }
}

// ---------------------------------------------------------------------------
// BF16 MFMA attention — r4-verified best (76.0 µs): 512 threads / 8 waves,
// wave = 16 q-rows. 16 waves/CU (4/SIMD).
//  - exp2-domain softmax (Q pre-scaled by 0.125*log2e).
//  - swapped QK^T: mfma(K,Q) -> S^T; reg r = consecutive keys at fixed q
//    -> 2x v_cvt_pk_bf16_f32 + one ds_write_b64 per nt.
//  - per-wave Ps [16][68], PV A-fragment via ds_read_b128.
//  - double-buffered K/V LDS (stride 72) + reg prefetch, one barrier/tile
//    (lgkmcnt(0) only, vmcnt stays in flight).
// Fuses +q residual and per-head LayerNorm. Writes fp32 X and bf16 Xb.
// ---------------------------------------------------------------------------
__global__ __launch_bounds__(512, 4) void attn_mfma_kernel(
    const short* __restrict__ Qb, const short* __restrict__ Kb, const short* __restrict__ Vt,
    const float* __restrict__ Qf, const int* __restrict__ mask,
    const float* __restrict__ g_att, const float* __restrict__ b_att,
    float* __restrict__ X, short* __restrict__ Xb)
{
    const int tid  = threadIdx.x;
    const int lane = tid & 63;
    const int wave = tid >> 6;          // 0..7
    const int quad = lane >> 4;
    const int l15  = lane & 15;

    const int h  = blockIdx.y;
    const int b  = blockIdx.z;
    const int q0 = blockIdx.x * 128;
    const int bS = b * SS;

    __shared__ __align__(16) short Ks[2 * 64 * 72];   // [buf][key][d]
    __shared__ __align__(16) short Vs[2 * 64 * 72];   // [buf][d][key]
    __shared__ __align__(16) short Ps[8 * 16 * 68];   // per-wave [q][key]
    __shared__ float smadd[2 * 64];

    // Q fragments (bf16, pre-scaled by 0.125*log2e) — B operand of swapped QK
    short8 qf[2];
#pragma unroll
    for (int s = 0; s < 2; s++)
        qf[s] = *(const short8*)(Qb +
            (size_t)(bS + q0 + wave * 16 + l15) * DD + h * 64 + s * 32 + quad * 8);

    floatx4 o[4];
#pragma unroll
    for (int nt = 0; nt < 4; nt++) o[nt] = (floatx4)0.0f;
    float lsum = 0.0f;                  // per-lane: sum over this lane's keys, q=l15

    // staging split: K+V tile = 512 chunks of 8 shorts over 512 threads -> 1+1
    const int srow = tid >> 3;          // 0..63
    const int sch  = tid & 7;

    // preload tile 0 into regs
    short8 kreg, vreg;
    float mreg;
    {
        kreg = *(const short8*)(Kb + (size_t)(bS + srow) * DD + h * 64 + sch * 8);
        vreg = *(const short8*)(Vt + (size_t)(b * 1024 + h * 64 + srow) * SS + sch * 8);
        mreg = (tid < 64) ? (float)mask[bS + tid] : 0.0f;
    }

    for (int kt = 0; kt < SS / 64; kt++) {
        const int bufo = (kt & 1) * (64 * 72);
        // commit staged regs for tile kt to LDS buf[kt&1]
        *(short8*)&Ks[bufo + srow * 72 + sch * 8] = kreg;
        *(short8*)&Vs[bufo + srow * 72 + sch * 8] = vreg;
        if (tid < 64) smadd[(kt & 1) * 64 + tid] = (1.0f - mreg) * -1e9f;

        // prefetch tile kt+1 into regs (stays in flight across the barrier)
        if (kt < SS / 64 - 1) {
            const int k0n = (kt + 1) * 64;
            kreg = *(const short8*)(Kb + (size_t)(bS + k0n + srow) * DD + h * 64 + sch * 8);
            vreg = *(const short8*)(Vt + (size_t)(b * 1024 + h * 64 + srow) * SS + k0n + sch * 8);
            mreg = (tid < 64) ? (float)mask[bS + k0n + tid] : 0.0f;
        }

        // raw barrier: drain LDS writes only (lgkmcnt 0), leave vmcnt in flight
        __builtin_amdgcn_s_waitcnt(0xC07F);
        __builtin_amdgcn_s_barrier();

        // S^T = K @ (Q*log2e/8)^T in log2 domain; P = exp2(S + madd).
        // Per nt: regs r are consecutive keys nt*16+quad*4+r at q = l15.
#pragma unroll
        for (int nt = 0; nt < 4; nt++) {
            const float4 mrow = *(const float4*)&smadd[(kt & 1) * 64 + nt * 16 + quad * 4];
            floatx4 acc = (floatx4)0.0f;
#pragma unroll
            for (int s = 0; s < 2; s++) {
                short8 kf = *(const short8*)&Ks[bufo + (nt * 16 + l15) * 72 + s * 32 + quad * 8];
                acc = __builtin_amdgcn_mfma_f32_16x16x32_bf16(kf, qf[s], acc, 0, 0, 0);
            }
            float p0 = __builtin_exp2f(acc[0] + mrow.x);
            float p1 = __builtin_exp2f(acc[1] + mrow.y);
            float p2 = __builtin_exp2f(acc[2] + mrow.z);
            float p3 = __builtin_exp2f(acc[3] + mrow.w);
            lsum += (p0 + p1) + (p2 + p3);
            unsigned w0 = cvtpk(p0, p1);
            unsigned w1 = cvtpk(p2, p3);
            *(uint2v*)&Ps[wave * 1088 + l15 * 68 + nt * 16 + quad * 4] = (uint2v){w0, w1};
        }

        // O += P @ V  (Ps per-wave; wave-internal lgkm ordering suffices)
#pragma unroll
        for (int s = 0; s < 2; s++) {
            short8 pa = *(const short8*)&Ps[wave * 1088 + l15 * 68 + s * 32 + quad * 8];
#pragma unroll
            for (int nt = 0; nt < 4; nt++) {
                short8 vb = *(const short8*)&Vs[bufo + (nt * 16 + l15) * 72 + s * 32 + quad * 8];
                o[nt] = __builtin_amdgcn_mfma_f32_16x16x32_bf16(pa, vb, o[nt], 0, 0, 0);
            }
        }
    }

    // lsum: reduce across quads (lanes with same l15 hold disjoint key subsets)
    lsum += __shfl_xor(lsum, 16);
    lsum += __shfl_xor(lsum, 32);
    // re-index by PV output row: lane needs 1/lsum at q = quad*4 + r
    float rlq[4];
#pragma unroll
    for (int r = 0; r < 4; r++)
        rlq[r] = 1.0f / __shfl(lsum, (lane & 48) | (quad * 4 + r));

    float gvv[4], bvv[4];
#pragma unroll
    for (int nt = 0; nt < 4; nt++) { gvv[nt] = g_att[nt * 16 + l15]; bvv[nt] = b_att[nt * 16 + l15]; }

    float x[4][4];
    float sum[4] = {0.f, 0.f, 0.f, 0.f};
#pragma unroll
    for (int r = 0; r < 4; r++) {
        const float rl = rlq[r];
        const int row = q0 + wave * 16 + quad * 4 + r;
        const size_t base = (size_t)(bS + row) * DD + h * 64;
#pragma unroll
        for (int nt = 0; nt < 4; nt++) {
            float xv = o[nt][r] * rl + Qf[base + nt * 16 + l15];
            x[nt][r] = xv;
            sum[r] += xv;
        }
    }
#pragma unroll
    for (int r = 0; r < 4; r++)
#pragma unroll
        for (int off = 1; off < 16; off <<= 1) sum[r] += __shfl_xor(sum[r], off);

    float vsum[4] = {0.f, 0.f, 0.f, 0.f}, mu[4];
#pragma unroll
    for (int r = 0; r < 4; r++) {
        mu[r] = sum[r] * (1.0f / 64.0f);
#pragma unroll
        for (int nt = 0; nt < 4; nt++) { float d = x[nt][r] - mu[r]; vsum[r] += d * d; }
    }
#pragma unroll
    for (int r = 0; r < 4; r++) {
#pragma unroll
        for (int off = 1; off < 16; off <<= 1) vsum[r] += __shfl_xor(vsum[r], off);
        float rstd = rsqrtf(vsum[r] * (1.0f / 64.0f) + 1e-5f);
        const int row = q0 + wave * 16 + quad * 4 + r;
        const size_t base = (size_t)(bS + row) * DD + h * 64;
#pragma unroll
        for (int nt = 0; nt < 4; nt++) {
            float yv = (x[nt][r] - mu[r]) * rstd * gvv[nt] + bvv[nt];
            X[base + nt * 16 + l15] = yv;
            Xb[base + nt * 16 + l15] = f2bf(yv);
        }
    }
}

// ---------------------------------------------------------------------------
// Final fused epilogue: Z = X + tanh(Y1 + Y2 - bres);  out = tanh(LN(Z, g, b))
// (Y1/Y2 are K-split GEMM partials, each carrying +bres — subtract one.)
// ---------------------------------------------------------------------------
__global__ __launch_bounds__(256) void lnout_kernel(
    const float* __restrict__ X, const float* __restrict__ Y1,
    const float* __restrict__ Y2, const float* __restrict__ bres,
    const float* __restrict__ g, const float* __restrict__ bcoef,
    float* __restrict__ out)
{
    const int r = blockIdx.x;
    const int t = threadIdx.x;
    const size_t base = (size_t)r * DD + (t << 2);
    float4 x  = ld4(X + base);
    float4 y1 = ld4(Y1 + base);
    float4 y2 = ld4(Y2 + base);
    float4 br = ld4(bres + (t << 2));
    float4 z;
    z.x = x.x + tanhf(y1.x + y2.x - br.x);
    z.y = x.y + tanhf(y1.y + y2.y - br.y);
    z.z = x.z + tanhf(y1.z + y2.z - br.z);
    z.w = x.w + tanhf(y1.w + y2.w - br.w);

    __shared__ float red[4];
    __shared__ float stats[2];
    const int w = t >> 6;

    float sv = z.x + z.y + z.z + z.w;
#pragma unroll
    for (int off = 32; off > 0; off >>= 1) sv += __shfl_down(sv, off);
    if ((t & 63) == 0) red[w] = sv;
    __syncthreads();
    if (t == 0) stats[0] = (red[0] + red[1] + red[2] + red[3]) * (1.0f / 1024.0f);
    __syncthreads();
    const float mu = stats[0];

    float4 d;
    d.x = z.x - mu; d.y = z.y - mu; d.z = z.z - mu; d.w = z.w - mu;
    float s2 = d.x * d.x + d.y * d.y + d.z * d.z + d.w * d.w;
#pragma unroll
    for (int off = 32; off > 0; off >>= 1) s2 += __shfl_down(s2, off);
    if ((t & 63) == 0) red[w] = s2;
    __syncthreads();
    if (t == 0) stats[1] = rsqrtf((red[0] + red[1] + red[2] + red[3]) * (1.0f / 1024.0f) + 1e-5f);
    __syncthreads();
    const float rstd = stats[1];

    float4 gv = ld4(g + (t << 2));
    float4 bv = ld4(bcoef + (t << 2));
    float4 o;
    o.x = tanhf(d.x * rstd * gv.x + bv.x);
    o.y = tanhf(d.y * rstd * gv.y + bv.y);
    o.z = tanhf(d.z * rstd * gv.z + bv.z);
    o.w = tanhf(d.w * rstd * gv.w + bv.w);
    *(float4*)(out + base) = o;
}

// ---------------------------------------------------------------------------
extern "C" void kernel_launch(void* const* d_in, const int* in_sizes, int n_in,
                              void* d_out, int out_size, void* d_ws, size_t ws_size,
                              hipStream_t stream)
{
    const float* query = (const float*)d_in[0];
    const float* key   = (const float*)d_in[1];
    const float* value = (const float*)d_in[2];
    const int*   mask  = (const int*)  d_in[3];
    const float* Wq    = (const float*)d_in[4];
    const float* bq    = (const float*)d_in[5];
    const float* Wk    = (const float*)d_in[6];
    const float* bk    = (const float*)d_in[7];
    const float* Wv    = (const float*)d_in[8];
    const float* bv    = (const float*)d_in[9];
    const float* g_att = (const float*)d_in[10];
    const float* b_att = (const float*)d_in[11];
    const float* Wres  = (const float*)d_in[12];
    const float* bres  = (const float*)d_in[13];
    const float* g_out = (const float*)d_in[14];
    const float* b_out = (const float*)d_in[15];

    const size_t MAT = (size_t)MROWS * DD;     // 4M elements
    float* fws = (float*)d_ws;
    // fp32 regions
    float* Qw = fws;                           // [0,4M)   fp32 Q residual
    float* Xw = fws + MAT;                     // [4M,8M)  attn out fp32
    // bf16 persistent regions (element = short)
    short* Qb = (short*)(fws + 2 * MAT);       // 2M floats (holds Q*0.125*log2e in bf16)
    short* Kb = Qb + MAT;
    short* Vt = Kb + MAT;                      // V^T [(b*1024+h*64+d)][S]
    // bf16 inputs to QKV GEMM (dead after) — reused later
    short* qbf = Vt + MAT;                     // 2M floats
    short* kbf = qbf + MAT;
    short* vbf = kbf + MAT;
    // weight transposes
    short* Wtq = vbf + MAT;                    // 0.5M floats each
    short* Wtk = Wtq + DD * DD;
    short* Wtv = Wtk + DD * DD;
    short* Wtr = Wtv + DD * DD;
    // aliases (stream-ordered safe):
    short* Xb = qbf;                           // attn bf16 out (qbf dead)
    float* Y1 = (float*)kbf;                   // res partial 1 (kbf+vbf dead post-attn)
    float* Y2 = Qw;                            // res partial 2 (Qw dead post-attn)

    // 1) fp32 -> bf16 activations
    convert_kernel<<<dim3(MAT / 2048, 1, 3), 256, 0, stream>>>(
        query, key, value, qbf, kbf, vbf);

    // 2) weight transpose-converts
    transpose_w_kernel<<<dim3(16, 16, 4), 256, 0, stream>>>(
        Wq, Wk, Wv, Wres, Wtq, Wtk, Wtv, Wtr);

    // 3) QKV projections, bf16 MFMA. Q: fp32 + bf16*(0.125*log2e); K; V^T
    gemm_bf16_kernel<<<dim3(8, 32, 3), 256, 0, stream>>>(
        qbf, kbf, vbf, Wtq, Wtk, Wtv, bq, bk, bv,
        Qw, nullptr, nullptr,
        Qb, Kb, nullptr,
        nullptr, nullptr, Vt,
        0.180336884f, 1.0f, 1.0f, 0);

    // 4) bf16 MFMA attention (exp2-domain softmax) + residual + per-head LN
    attn_mfma_kernel<<<dim3(SS / 128, HH, BB), 512, 0, stream>>>(
        Qb, Kb, Vt, Qw, mask, g_att, b_att, Xw, Xb);

    // 5) res branch GEMM, K-split x2: Y1/Y2 partials (each +bres)
    gemm_bf16_kernel<<<dim3(8, 32, 2), 256, 0, stream>>>(
        Xb, Xb, Xb, Wtr, Wtr, Wtr, bres, bres, bres,
        Y1, Y2, nullptr, nullptr, nullptr, nullptr, nullptr, nullptr, nullptr,
        1.0f, 1.0f, 1.0f, 1);

    // 6) Z = X + tanh(Y1+Y2-bres); out = tanh(LN(Z))
    lnout_kernel<<<MROWS, 256, 0, stream>>>(Xw, Y1, Y2, bres, g_out, b_out, (float*)d_out);
}